// Round 1
// baseline (3781.288 us; speedup 1.0000x reference)
//
#include <hip/hip_runtime.h>
#include <math.h>

#define M_PTS 29696
#define N_IN_DIM 1024
#define KCL 100
#define NZ_DIM 32

// ---------------- GEMM: C = act(A @ W + bias) ----------------
// A: MxK row-major, W: KxN row-major, C: MxN row-major.
template<int BM, int BN, int BK, int TM, int TN, bool RELU>
__global__ __launch_bounds__((BM/TM)*(BN/TN))
void gemm_bias(const float* __restrict__ A, const float* __restrict__ W,
               const float* __restrict__ bias, float* __restrict__ C,
               int M, int N, int K)
{
    constexpr int THREADS = (BM/TM)*(BN/TN);
    __shared__ float As[BK][BM];   // transposed A tile: As[k][m]
    __shared__ float Ws[BK][BN];
    const int tid = threadIdx.x;
    const int tx = tid % (BN/TN);
    const int ty = tid / (BN/TN);
    const int row0 = blockIdx.y * BM + ty*TM;
    const int col0 = blockIdx.x * BN + tx*TN;
    float acc[TM][TN] = {};
    constexpr int A_VECS = (BM*BK)/(THREADS*4);
    constexpr int W_ELEMS = (BK*BN)/THREADS;
    for (int k0 = 0; k0 < K; k0 += BK) {
        __syncthreads();
        #pragma unroll
        for (int v = 0; v < A_VECS; ++v) {
            int flat = (tid + v*THREADS)*4;
            int r = flat / BK, c = flat % BK;
            const float4 a4 = *(const float4*)(A + (size_t)(blockIdx.y*BM + r)*K + (k0 + c));
            As[c+0][r] = a4.x; As[c+1][r] = a4.y; As[c+2][r] = a4.z; As[c+3][r] = a4.w;
        }
        #pragma unroll
        for (int e = 0; e < W_ELEMS; ++e) {
            int flat = tid + e*THREADS;
            int r = flat / BN, c = flat % BN;
            Ws[r][c] = W[(size_t)(k0 + r)*N + blockIdx.x*BN + c];
        }
        __syncthreads();
        #pragma unroll
        for (int kk = 0; kk < BK; ++kk) {
            float af[TM], bf[TN];
            #pragma unroll
            for (int i = 0; i < TM; ++i) af[i] = As[kk][ty*TM + i];
            #pragma unroll
            for (int j = 0; j < TN; ++j) bf[j] = Ws[kk][tx*TN + j];
            #pragma unroll
            for (int i = 0; i < TM; ++i)
                #pragma unroll
                for (int j = 0; j < TN; ++j)
                    acc[i][j] = fmaf(af[i], bf[j], acc[i][j]);
        }
    }
    #pragma unroll
    for (int i = 0; i < TM; ++i) {
        #pragma unroll
        for (int j = 0; j < TN; ++j) {
            float v = acc[i][j] + bias[col0 + j];
            if (RELU) v = fmaxf(v, 0.0f);
            C[(size_t)(row0 + i)*N + (col0 + j)] = v;
        }
    }
}

// ---------------- accumulator zeroing ----------------
__global__ void zero_acc(float* __restrict__ u, int* __restrict__ cnt, double* __restrict__ dbl)
{
    int t = threadIdx.x;
    if (t < KCL) { u[t] = 0.0f; cnt[t] = 0; }
    if (t < 8) dbl[t] = 0.0;
}

// ---------------- per-point clustering pass ----------------
// zp = standardize(z * cos_mult); dist to clusters; q = (eps+dist)/rowsum;
// predict = argmax; accumulate u[k], cnt[pred], S.
__global__ __launch_bounds__(256)
void cluster_pass(const float* __restrict__ z, const float* __restrict__ t1,
                  const float* __restrict__ clusters, float* __restrict__ q,
                  float* __restrict__ pred_out, float* __restrict__ u_acc,
                  int* __restrict__ cnt, double* __restrict__ S_acc)
{
    __shared__ float cl[KCL*NZ_DIM];
    __shared__ float u_s[KCL];
    __shared__ float swave[4];
    const int tid = threadIdx.x;
    for (int i = tid; i < KCL*NZ_DIM; i += 256) cl[i] = clusters[i];
    if (tid < KCL) u_s[tid] = 0.0f;
    __syncthreads();

    const int p = blockIdx.x*256 + tid;
    float zr[NZ_DIM];
    const float a = t1[p*3+0]*0.01f, b = t1[p*3+1]*0.01f, c = t1[p*3+2]*0.01f;
    const float cm = a*b*c*0.99f + 1.0f;
    float mean = 0.0f;
    #pragma unroll
    for (int i = 0; i < NZ_DIM; ++i) { zr[i] = z[(size_t)p*NZ_DIM+i]*cm; mean += zr[i]; }
    mean *= (1.0f/NZ_DIM);
    float var = 0.0f;
    #pragma unroll
    for (int i = 0; i < NZ_DIM; ++i) { float d = zr[i]-mean; var += d*d; }
    const float istd = 1.0f / sqrtf(var * (1.0f/(NZ_DIM-1)));
    #pragma unroll
    for (int i = 0; i < NZ_DIM; ++i) zr[i] = (zr[i]-mean)*istd;

    float rowsum = 0.0f, best = -1.0f; int bi = 0;
    float* qrow = q + (size_t)p*KCL;
    for (int k = 0; k < KCL; ++k) {
        float d = 0.0f;
        #pragma unroll
        for (int i = 0; i < NZ_DIM; ++i) { float t = zr[i]-cl[k*NZ_DIM+i]; d = fmaf(t,t,d); }
        float val = 1e-5f + d;     // = q ** (-(v+1)/2) of reference (exponent = -1)
        rowsum += val;
        if (val > best) { best = val; bi = k; }
        qrow[k] = val;
    }
    pred_out[p] = (float)bi;
    atomicAdd(&cnt[bi], 1);

    const float inv_rs = 1.0f/rowsum;
    float Sp = 0.0f;
    for (int k = 0; k < KCL; ++k) {
        float qv = qrow[k]*inv_rs;
        qrow[k] = qv;
        atomicAdd(&u_s[k], qv);
        float lq = logf(qv);
        float om = 1.0f - qv;
        float tq = om*om*lq*(float)M_PTS;      // temp_q (negative)
        Sp += sqrtf(-1.0f/tq);
    }
    for (int off = 32; off > 0; off >>= 1) Sp += __shfl_down(Sp, off, 64);
    if ((tid & 63) == 0) swave[tid >> 6] = Sp;
    __syncthreads();
    if (tid < KCL) atomicAdd(&u_acc[tid], u_s[tid]);
    if (tid == 0) atomicAdd(S_acc, (double)(swave[0]+swave[1]+swave[2]+swave[3]));
}

// ---------------- block reduction helpers (256 threads) ----------------
__device__ __forceinline__ float blk_sum(float v, float* sh) {
    int tid = threadIdx.x;
    sh[tid] = v; __syncthreads();
    for (int s = 128; s > 0; s >>= 1) { if (tid < s) sh[tid] += sh[tid+s]; __syncthreads(); }
    float r = sh[0]; __syncthreads();
    return r;
}
__device__ __forceinline__ float blk_min(float v, float* sh) {
    int tid = threadIdx.x;
    sh[tid] = v; __syncthreads();
    for (int s = 128; s > 0; s >>= 1) { if (tid < s) sh[tid] = fminf(sh[tid], sh[tid+s]); __syncthreads(); }
    float r = sh[0]; __syncthreads();
    return r;
}

// ---------------- finalize u, v, f and u_loss ----------------
__global__ __launch_bounds__(256)
void finalize_kernel(const float* __restrict__ u_in, const int* __restrict__ cnt,
                     const double* __restrict__ dbl, const float* __restrict__ clusters,
                     float* __restrict__ f_out, double* __restrict__ dbl_out)
{
    __shared__ float sh[256];
    __shared__ double shd[256];
    const int tid = threadIdx.x;
    const bool act = (tid < KCL);
    const float S = (float)dbl[0];

    float uv = act ? u_in[tid] : 0.0f;
    float um = blk_sum(uv, sh) * (1.0f/KCL);
    float ud = act ? (uv - um) : 0.0f;
    float uvar = blk_sum(ud*ud, sh) * (1.0f/(KCL-1));
    float un = ud / sqrtf(uvar);
    float umin = blk_min(act ? un : 3.0e38f, sh);
    float ufin = un - umin + 0.001f;

    float vv = 0.0f;
    if (act) { int cc = cnt[tid]; if (cc < 1) cc = 1; vv = sqrtf((float)cc) * S; }
    float vm = blk_sum(vv, sh) * (1.0f/KCL);
    float vd = act ? (vv - vm) : 0.0f;
    float vvar = blk_sum(vd*vd, sh) * (1.0f/(KCL-1));
    float vn = vd / sqrtf(vvar);
    float vmin = blk_min(act ? vn : 3.0e38f, sh);
    float vfin = vn - vmin + 0.001f;

    if (act) f_out[tid] = ufin + vfin + 1.0f;   // f = u + v + C_CONST

    // pairwise cluster distance sum (D.sum() over 100x100)
    double dp = 0.0;
    for (int pair = tid; pair < KCL*KCL; pair += 256) {
        int i = pair / KCL, j = pair % KCL;
        float d = 0.0f;
        #pragma unroll
        for (int t2 = 0; t2 < NZ_DIM; ++t2) {
            float x = clusters[i*NZ_DIM+t2] - clusters[j*NZ_DIM+t2];
            d = fmaf(x, x, d);
        }
        dp += (double)d;
    }
    shd[tid] = dp; __syncthreads();
    for (int s = 128; s > 0; s >>= 1) { if (tid < s) shd[tid] += shd[tid+s]; __syncthreads(); }
    if (tid == 0) {
        // u_loss = 0.01 / (Dsum / 9900)
        dbl_out[3] = 0.01 * (double)(KCL*KCL - KCL) / shd[0];
    }
}

// ---------------- KL pass ----------------
__global__ __launch_bounds__(256)
void kl_pass(const float* __restrict__ q, const float* __restrict__ f,
             double* __restrict__ kl_acc)
{
    __shared__ float fs[KCL];
    __shared__ float swave[4];
    const int tid = threadIdx.x;
    if (tid < KCL) fs[tid] = f[tid];
    __syncthreads();
    const size_t p = (size_t)blockIdx.x*256 + tid;
    const float* qr = q + p*KCL;
    float s = 0.0f;
    for (int k = 0; k < KCL; ++k) { float qv = qr[k]; s += qv*qv/fs[k]; }
    const float inv_s = 1.0f/s;
    float klp = 0.0f;
    for (int k = 0; k < KCL; ++k) {
        float qv = qr[k];
        float w = qv*qv/fs[k];
        float pv = w*inv_s;
        klp += pv*(logf(pv) - logf(qv));
    }
    for (int off = 32; off > 0; off >>= 1) klp += __shfl_down(klp, off, 64);
    if ((tid & 63) == 0) swave[tid >> 6] = klp;
    __syncthreads();
    if (tid == 0) atomicAdd(kl_acc, (double)(swave[0]+swave[1]+swave[2]+swave[3]));
}

// ---------------- reconstruction loss pass ----------------
__global__ __launch_bounds__(256)
void re_pass(const float* __restrict__ xb, const float* __restrict__ x,
             double* __restrict__ acc, int n)
{
    __shared__ float swave[4];
    float part = 0.0f;
    for (size_t i = (size_t)blockIdx.x*blockDim.x + threadIdx.x; i < (size_t)n;
         i += (size_t)gridDim.x*blockDim.x) {
        float d = xb[i] - x[i];
        part = fmaf(d, d, part);
    }
    for (int off = 32; off > 0; off >>= 1) part += __shfl_down(part, off, 64);
    const int tid = threadIdx.x;
    if ((tid & 63) == 0) swave[tid >> 6] = part;
    __syncthreads();
    if (tid == 0) atomicAdd(acc, (double)(swave[0]+swave[1]+swave[2]+swave[3]));
}

// ---------------- final loss ----------------
__global__ void final_loss(const double* __restrict__ dbl, float* __restrict__ out)
{
    // dbl: [0]=S, [1]=kl_sum, [2]=re_sum, [3]=u_loss
    double kl = dbl[1] / (double)((size_t)M_PTS*KCL) * 0.01;
    double re = dbl[2] / (double)((size_t)M_PTS*N_IN_DIM);
    out[0] = (float)(kl + re + dbl[3]);
}

extern "C" void kernel_launch(void* const* d_in, const int* in_sizes, int n_in,
                              void* d_out, int out_size, void* d_ws, size_t ws_size,
                              hipStream_t stream)
{
    const float* x   = (const float*)d_in[0];
    const float* t1c = (const float*)d_in[1];
    const float* clu = (const float*)d_in[2];
    const float* We1 = (const float*)d_in[3];  const float* be1 = (const float*)d_in[4];
    const float* We2 = (const float*)d_in[5];  const float* be2 = (const float*)d_in[6];
    const float* We3 = (const float*)d_in[7];  const float* be3 = (const float*)d_in[8];
    const float* Wz  = (const float*)d_in[9];  const float* bz  = (const float*)d_in[10];
    const float* Wd1 = (const float*)d_in[11]; const float* bd1 = (const float*)d_in[12];
    const float* Wd2 = (const float*)d_in[13]; const float* bd2 = (const float*)d_in[14];
    const float* Wd3 = (const float*)d_in[15]; const float* bd3 = (const float*)d_in[16];
    const float* Wxb = (const float*)d_in[17]; const float* bxb = (const float*)d_in[18];
    float* out = (float*)d_out;

    const size_t M = M_PTS;
    float* ws   = (float*)d_ws;
    float* BIG  = ws;                          // M*2048 floats (h3, then d1, then x_bar)
    float* MID1 = BIG  + M*2048;               // M*512  (h1, then d2)
    float* MID2 = MID1 + M*512;                // M*512  (h2, then d3)
    float* Z    = MID2 + M*512;                // M*32
    float* Q    = Z    + M*32;                 // M*100
    float* U    = Q    + M*KCL;                // 100 (+pad)
    float* F    = U    + 128;                  // 100 (+pad)
    int*   CNT  = (int*)(F + 128);             // 100 (+pad)
    double* DBL = (double*)(CNT + 128);        // 8 doubles (8B-aligned: even float offset)

    zero_acc<<<1, 256, 0, stream>>>(U, CNT, DBL);

    dim3 blk(256);
    // h1 = relu(x @ We1 + be1)
    gemm_bias<128,64,16,8,4,true ><<<dim3(512/64,  M/128), blk, 0, stream>>>(x,    We1, be1, MID1, M, 512,  1024);
    // h2 = relu(h1 @ We2 + be2)
    gemm_bias<128,64,16,8,4,true ><<<dim3(512/64,  M/128), blk, 0, stream>>>(MID1, We2, be2, MID2, M, 512,  512);
    // h3 = relu(h2 @ We3 + be3)
    gemm_bias<128,64,16,8,4,true ><<<dim3(2048/64, M/128), blk, 0, stream>>>(MID2, We3, be3, BIG,  M, 2048, 512);
    // z = h3 @ Wz + bz
    gemm_bias<128,32,16,8,2,false><<<dim3(1,       M/128), blk, 0, stream>>>(BIG,  Wz,  bz,  Z,    M, 32,   2048);
    // d1 = relu(z @ Wd1 + bd1)   (overwrites h3)
    gemm_bias<128,64,16,8,4,true ><<<dim3(2048/64, M/128), blk, 0, stream>>>(Z,    Wd1, bd1, BIG,  M, 2048, 32);
    // d2 = relu(d1 @ Wd2 + bd2)  (overwrites h1)
    gemm_bias<128,64,16,8,4,true ><<<dim3(512/64,  M/128), blk, 0, stream>>>(BIG,  Wd2, bd2, MID1, M, 512,  2048);
    // d3 = relu(d2 @ Wd3 + bd3)  (overwrites h2)
    gemm_bias<128,64,16,8,4,true ><<<dim3(512/64,  M/128), blk, 0, stream>>>(MID1, Wd3, bd3, MID2, M, 512,  512);
    // x_bar = d3 @ Wxb + bxb     (overwrites d1)
    gemm_bias<128,64,16,8,4,false><<<dim3(1024/64, M/128), blk, 0, stream>>>(MID2, Wxb, bxb, BIG,  M, 1024, 512);

    cluster_pass<<<M/256, 256, 0, stream>>>(Z, t1c, clu, Q, out, U, CNT, DBL + 0);
    finalize_kernel<<<1, 256, 0, stream>>>(U, CNT, DBL, clu, F, DBL);
    kl_pass<<<M/256, 256, 0, stream>>>(Q, F, DBL + 1);
    re_pass<<<1024, 256, 0, stream>>>(BIG, x, DBL + 2, (int)(M*N_IN_DIM));
    final_loss<<<1, 1, 0, stream>>>(DBL, out + M_PTS);
}

// Round 2
// 1732.636 us; speedup vs baseline: 2.1824x; 2.1824x over previous
//
#include <hip/hip_runtime.h>
#include <math.h>

#define M_PTS 29696
#define N_IN_DIM 1024
#define KCL 100
#define NZ_DIM 32

typedef _Float16 h8 __attribute__((ext_vector_type(8)));
typedef _Float16 h4 __attribute__((ext_vector_type(4)));
typedef float f4 __attribute__((ext_vector_type(4)));

// ---------------- weight transpose: W (KxN) -> WT (NxK), fp32 ----------------
__global__ __launch_bounds__(256)
void transpose_w(const float* __restrict__ W, float* __restrict__ WT, int K, int N)
{
    __shared__ float t[32][33];
    const int tid = threadIdx.x;
    const int n0 = blockIdx.x * 32, k0 = blockIdx.y * 32;
    {
        int r = tid / 8, c = (tid % 8) * 4;
        const float4 v = *(const float4*)(W + (size_t)(k0 + r) * N + n0 + c);
        t[r][c+0] = v.x; t[r][c+1] = v.y; t[r][c+2] = v.z; t[r][c+3] = v.w;
    }
    __syncthreads();
    {
        int r = tid / 8, c = (tid % 8) * 4;   // r = n idx, c = k idx
        float4 v;
        v.x = t[c+0][r]; v.y = t[c+1][r]; v.z = t[c+2][r]; v.w = t[c+3][r];
        *(float4*)(WT + (size_t)(n0 + r) * K + k0 + c) = v;
    }
}

// ---------------- MFMA GEMM: C = act(A @ WT^T + bias), f16x3 split ----------------
// A: MxK fp32 row-major; WT: NxK fp32 row-major; C: MxN fp32.
template<int WM, int WN, int TM, int TN, bool RELU>
__global__ __launch_bounds__(WM*WN*64)
void gemm_mfma(const float* __restrict__ A, const float* __restrict__ WT,
               const float* __restrict__ bias, float* __restrict__ C,
               int M, int N, int K)
{
    constexpr int BM = WM*TM*16;
    constexpr int BN = WN*TN*16;
    constexpr int THREADS = WM*WN*64;
    constexpr int LDK = 40;   // 32 + 8 pad (breaks pow2 bank stride, keeps 16B align)
    __shared__ __align__(16) _Float16 Ah[BM*LDK];
    __shared__ __align__(16) _Float16 Al[BM*LDK];
    __shared__ __align__(16) _Float16 Bh[BN*LDK];
    __shared__ __align__(16) _Float16 Bl[BN*LDK];

    const int tid = threadIdx.x;
    const int bm0 = blockIdx.y * BM;
    const int bn0 = blockIdx.x * BN;
    const int wave = tid >> 6, lane = tid & 63;
    const int wm = wave / WN, wn = wave % WN;
    const int lrow = lane & 15, lq = lane >> 4;

    f4 acc[TM][TN];
    #pragma unroll
    for (int i = 0; i < TM; ++i)
        #pragma unroll
        for (int j = 0; j < TN; ++j)
            acc[i][j] = (f4)0.0f;

    for (int k0 = 0; k0 < K; k0 += 32) {
        __syncthreads();
        // ---- stage A tile (BMx32) with on-the-fly f16 hi/lo split ----
        #pragma unroll
        for (int it = 0; it < (BM*32)/(THREADS*4); ++it) {
            int idx = (tid + it*THREADS) * 4;
            int r = idx >> 5, c = idx & 31;
            const float4 v = *(const float4*)(A + (size_t)(bm0 + r)*K + k0 + c);
            float vv[4] = {v.x, v.y, v.z, v.w};
            h4 hi, lo;
            #pragma unroll
            for (int u = 0; u < 4; ++u) {
                _Float16 h = (_Float16)vv[u];
                hi[u] = h;
                lo[u] = (_Float16)(vv[u] - (float)h);
            }
            *(h4*)(&Ah[r*LDK + c]) = hi;
            *(h4*)(&Al[r*LDK + c]) = lo;
        }
        // ---- stage B tile (BNx32) from WT ----
        #pragma unroll
        for (int it = 0; it < (BN*32)/(THREADS*4); ++it) {
            int idx = (tid + it*THREADS) * 4;
            int r = idx >> 5, c = idx & 31;
            const float4 v = *(const float4*)(WT + (size_t)(bn0 + r)*K + k0 + c);
            float vv[4] = {v.x, v.y, v.z, v.w};
            h4 hi, lo;
            #pragma unroll
            for (int u = 0; u < 4; ++u) {
                _Float16 h = (_Float16)vv[u];
                hi[u] = h;
                lo[u] = (_Float16)(vv[u] - (float)h);
            }
            *(h4*)(&Bh[r*LDK + c]) = hi;
            *(h4*)(&Bl[r*LDK + c]) = lo;
        }
        __syncthreads();
        // ---- fragments ----
        h8 ah[TM], al[TM], bh[TN], bl[TN];
        #pragma unroll
        for (int i = 0; i < TM; ++i) {
            int row = (wm*TM + i)*16 + lrow;
            ah[i] = *(const h8*)(&Ah[row*LDK + lq*8]);
            al[i] = *(const h8*)(&Al[row*LDK + lq*8]);
        }
        #pragma unroll
        for (int j = 0; j < TN; ++j) {
            int row = (wn*TN + j)*16 + lrow;
            bh[j] = *(const h8*)(&Bh[row*LDK + lq*8]);
            bl[j] = *(const h8*)(&Bl[row*LDK + lq*8]);
        }
        // ---- 3-term MFMA (terms separated to break acc dependency chains) ----
        #pragma unroll
        for (int i = 0; i < TM; ++i)
            #pragma unroll
            for (int j = 0; j < TN; ++j)
                acc[i][j] = __builtin_amdgcn_mfma_f32_16x16x32_f16(ah[i], bh[j], acc[i][j], 0, 0, 0);
        #pragma unroll
        for (int i = 0; i < TM; ++i)
            #pragma unroll
            for (int j = 0; j < TN; ++j)
                acc[i][j] = __builtin_amdgcn_mfma_f32_16x16x32_f16(ah[i], bl[j], acc[i][j], 0, 0, 0);
        #pragma unroll
        for (int i = 0; i < TM; ++i)
            #pragma unroll
            for (int j = 0; j < TN; ++j)
                acc[i][j] = __builtin_amdgcn_mfma_f32_16x16x32_f16(al[i], bh[j], acc[i][j], 0, 0, 0);
    }
    // ---- epilogue: D[row=(lane>>4)*4+reg][col=lane&15] per 16x16 tile ----
    #pragma unroll
    for (int j = 0; j < TN; ++j) {
        int col = bn0 + (wn*TN + j)*16 + lrow;
        float bj = bias[col];
        #pragma unroll
        for (int i = 0; i < TM; ++i) {
            int rbase = bm0 + (wm*TM + i)*16 + lq*4;
            #pragma unroll
            for (int r = 0; r < 4; ++r) {
                float v = acc[i][j][r] + bj;
                if (RELU) v = fmaxf(v, 0.0f);
                C[(size_t)(rbase + r)*N + col] = v;
            }
        }
    }
}

// ---------------- accumulator zeroing ----------------
__global__ void zero_acc(float* __restrict__ u, int* __restrict__ cnt, double* __restrict__ dbl)
{
    int t = threadIdx.x;
    if (t < KCL) { u[t] = 0.0f; cnt[t] = 0; }
    if (t < 8) dbl[t] = 0.0;
}

// ---------------- per-point clustering pass (argmax, u, cnt, S) ----------------
__global__ __launch_bounds__(256)
void cluster_pass(const float* __restrict__ z, const float* __restrict__ t1,
                  const float* __restrict__ clusters,
                  float* __restrict__ pred_out, float* __restrict__ u_acc,
                  int* __restrict__ cnt, double* __restrict__ S_acc)
{
    __shared__ float cl[KCL*NZ_DIM];
    __shared__ float u_s[KCL];
    __shared__ float swave[4];
    const int tid = threadIdx.x;
    for (int i = tid; i < KCL*NZ_DIM; i += 256) cl[i] = clusters[i];
    if (tid < KCL) u_s[tid] = 0.0f;
    __syncthreads();

    const int p = blockIdx.x*256 + tid;
    float zr[NZ_DIM];
    const float a = t1[p*3+0]*0.01f, b = t1[p*3+1]*0.01f, c = t1[p*3+2]*0.01f;
    const float cm = a*b*c*0.99f + 1.0f;
    float mean = 0.0f;
    #pragma unroll
    for (int i = 0; i < NZ_DIM; ++i) { zr[i] = z[(size_t)p*NZ_DIM+i]*cm; mean += zr[i]; }
    mean *= (1.0f/NZ_DIM);
    float var = 0.0f;
    #pragma unroll
    for (int i = 0; i < NZ_DIM; ++i) { float d = zr[i]-mean; var += d*d; }
    const float istd = 1.0f / sqrtf(var * (1.0f/(NZ_DIM-1)));
    #pragma unroll
    for (int i = 0; i < NZ_DIM; ++i) zr[i] = (zr[i]-mean)*istd;

    // pass 1: rowsum + argmax
    float rowsum = 0.0f, best = -1.0f; int bi = 0;
    for (int k = 0; k < KCL; ++k) {
        float d = 0.0f;
        #pragma unroll
        for (int i = 0; i < NZ_DIM; ++i) { float t = zr[i]-cl[k*NZ_DIM+i]; d = fmaf(t,t,d); }
        float val = 1e-5f + d;
        rowsum += val;
        if (val > best) { best = val; bi = k; }
    }
    pred_out[p] = (float)bi;
    atomicAdd(&cnt[bi], 1);

    // pass 2: u and S
    const float inv_rs = 1.0f/rowsum;
    float Sp = 0.0f;
    for (int k = 0; k < KCL; ++k) {
        float d = 0.0f;
        #pragma unroll
        for (int i = 0; i < NZ_DIM; ++i) { float t = zr[i]-cl[k*NZ_DIM+i]; d = fmaf(t,t,d); }
        float qv = (1e-5f + d)*inv_rs;
        atomicAdd(&u_s[k], qv);
        float lq = logf(qv);
        float om = 1.0f - qv;
        float tq = om*om*lq*(float)M_PTS;      // temp_q (negative)
        Sp += sqrtf(-1.0f/tq);
    }
    for (int off = 32; off > 0; off >>= 1) Sp += __shfl_down(Sp, off, 64);
    if ((tid & 63) == 0) swave[tid >> 6] = Sp;
    __syncthreads();
    if (tid < KCL) atomicAdd(&u_acc[tid], u_s[tid]);
    if (tid == 0) atomicAdd(S_acc, (double)(swave[0]+swave[1]+swave[2]+swave[3]));
}

// ---------------- block reduction helpers (256 threads) ----------------
__device__ __forceinline__ float blk_sum(float v, float* sh) {
    int tid = threadIdx.x;
    sh[tid] = v; __syncthreads();
    for (int s = 128; s > 0; s >>= 1) { if (tid < s) sh[tid] += sh[tid+s]; __syncthreads(); }
    float r = sh[0]; __syncthreads();
    return r;
}
__device__ __forceinline__ float blk_min(float v, float* sh) {
    int tid = threadIdx.x;
    sh[tid] = v; __syncthreads();
    for (int s = 128; s > 0; s >>= 1) { if (tid < s) sh[tid] = fminf(sh[tid], sh[tid+s]); __syncthreads(); }
    float r = sh[0]; __syncthreads();
    return r;
}

// ---------------- finalize u, v, f and u_loss ----------------
__global__ __launch_bounds__(256)
void finalize_kernel(const float* __restrict__ u_in, const int* __restrict__ cnt,
                     const double* __restrict__ dbl, const float* __restrict__ clusters,
                     float* __restrict__ f_out, double* __restrict__ dbl_out)
{
    __shared__ float sh[256];
    __shared__ double shd[256];
    const int tid = threadIdx.x;
    const bool act = (tid < KCL);
    const float S = (float)dbl[0];

    float uv = act ? u_in[tid] : 0.0f;
    float um = blk_sum(uv, sh) * (1.0f/KCL);
    float ud = act ? (uv - um) : 0.0f;
    float uvar = blk_sum(ud*ud, sh) * (1.0f/(KCL-1));
    float un = ud / sqrtf(uvar);
    float umin = blk_min(act ? un : 3.0e38f, sh);
    float ufin = un - umin + 0.001f;

    float vv = 0.0f;
    if (act) { int cc = cnt[tid]; if (cc < 1) cc = 1; vv = sqrtf((float)cc) * S; }
    float vm = blk_sum(vv, sh) * (1.0f/KCL);
    float vd = act ? (vv - vm) : 0.0f;
    float vvar = blk_sum(vd*vd, sh) * (1.0f/(KCL-1));
    float vn = vd / sqrtf(vvar);
    float vmin = blk_min(act ? vn : 3.0e38f, sh);
    float vfin = vn - vmin + 0.001f;

    if (act) f_out[tid] = ufin + vfin + 1.0f;   // f = u + v + C_CONST

    double dp = 0.0;
    for (int pair = tid; pair < KCL*KCL; pair += 256) {
        int i = pair / KCL, j = pair % KCL;
        float d = 0.0f;
        #pragma unroll
        for (int t2 = 0; t2 < NZ_DIM; ++t2) {
            float x = clusters[i*NZ_DIM+t2] - clusters[j*NZ_DIM+t2];
            d = fmaf(x, x, d);
        }
        dp += (double)d;
    }
    shd[tid] = dp; __syncthreads();
    for (int s = 128; s > 0; s >>= 1) { if (tid < s) shd[tid] += shd[tid+s]; __syncthreads(); }
    if (tid == 0) {
        dbl_out[3] = 0.01 * (double)(KCL*KCL - KCL) / shd[0];
    }
}

// ---------------- KL pass (recomputes q; rowsum cancels in p) ----------------
__global__ __launch_bounds__(256)
void kl_pass(const float* __restrict__ z, const float* __restrict__ t1,
             const float* __restrict__ clusters, const float* __restrict__ f,
             double* __restrict__ kl_acc)
{
    __shared__ float cl[KCL*NZ_DIM];
    __shared__ float fs[KCL], lfs[KCL];
    __shared__ float swave[4];
    const int tid = threadIdx.x;
    for (int i = tid; i < KCL*NZ_DIM; i += 256) cl[i] = clusters[i];
    if (tid < KCL) { float fv = f[tid]; fs[tid] = fv; lfs[tid] = logf(fv); }
    __syncthreads();

    const int p = blockIdx.x*256 + tid;
    float zr[NZ_DIM];
    const float a = t1[p*3+0]*0.01f, b = t1[p*3+1]*0.01f, c = t1[p*3+2]*0.01f;
    const float cm = a*b*c*0.99f + 1.0f;
    float mean = 0.0f;
    #pragma unroll
    for (int i = 0; i < NZ_DIM; ++i) { zr[i] = z[(size_t)p*NZ_DIM+i]*cm; mean += zr[i]; }
    mean *= (1.0f/NZ_DIM);
    float var = 0.0f;
    #pragma unroll
    for (int i = 0; i < NZ_DIM; ++i) { float d = zr[i]-mean; var += d*d; }
    const float istd = 1.0f / sqrtf(var * (1.0f/(NZ_DIM-1)));
    #pragma unroll
    for (int i = 0; i < NZ_DIM; ++i) zr[i] = (zr[i]-mean)*istd;

    // pass 1: rowsum and sv = sum(val^2 / f)
    float rowsum = 0.0f, sv = 0.0f;
    for (int k = 0; k < KCL; ++k) {
        float d = 0.0f;
        #pragma unroll
        for (int i = 0; i < NZ_DIM; ++i) { float t = zr[i]-cl[k*NZ_DIM+i]; d = fmaf(t,t,d); }
        float val = 1e-5f + d;
        rowsum += val;
        sv += val*val/fs[k];
    }
    const float lrs = logf(rowsum), lsv = logf(sv);
    const float inv_sv = 1.0f/sv;
    // pass 2: kl terms. p_k = (val^2/f)/sv ; log p - log q = lv - lf - lsv + lrs
    float klp = 0.0f;
    for (int k = 0; k < KCL; ++k) {
        float d = 0.0f;
        #pragma unroll
        for (int i = 0; i < NZ_DIM; ++i) { float t = zr[i]-cl[k*NZ_DIM+i]; d = fmaf(t,t,d); }
        float val = 1e-5f + d;
        float pv = val*val/fs[k]*inv_sv;
        klp += pv*(logf(val) - lfs[k] - lsv + lrs);
    }
    for (int off = 32; off > 0; off >>= 1) klp += __shfl_down(klp, off, 64);
    if ((tid & 63) == 0) swave[tid >> 6] = klp;
    __syncthreads();
    if (tid == 0) atomicAdd(kl_acc, (double)(swave[0]+swave[1]+swave[2]+swave[3]));
}

// ---------------- reconstruction loss pass ----------------
__global__ __launch_bounds__(256)
void re_pass(const float* __restrict__ xb, const float* __restrict__ x,
             double* __restrict__ acc, int n)
{
    __shared__ float swave[4];
    float part = 0.0f;
    for (size_t i = (size_t)blockIdx.x*blockDim.x + threadIdx.x; i < (size_t)n;
         i += (size_t)gridDim.x*blockDim.x) {
        float d = xb[i] - x[i];
        part = fmaf(d, d, part);
    }
    for (int off = 32; off > 0; off >>= 1) part += __shfl_down(part, off, 64);
    const int tid = threadIdx.x;
    if ((tid & 63) == 0) swave[tid >> 6] = part;
    __syncthreads();
    if (tid == 0) atomicAdd(acc, (double)(swave[0]+swave[1]+swave[2]+swave[3]));
}

// ---------------- final loss ----------------
__global__ void final_loss(const double* __restrict__ dbl, float* __restrict__ out)
{
    double kl = dbl[1] / (double)((size_t)M_PTS*KCL) * 0.01;
    double re = dbl[2] / (double)((size_t)M_PTS*N_IN_DIM);
    out[0] = (float)(kl + re + dbl[3]);
}

extern "C" void kernel_launch(void* const* d_in, const int* in_sizes, int n_in,
                              void* d_out, int out_size, void* d_ws, size_t ws_size,
                              hipStream_t stream)
{
    const float* x   = (const float*)d_in[0];
    const float* t1c = (const float*)d_in[1];
    const float* clu = (const float*)d_in[2];
    const float* We1 = (const float*)d_in[3];  const float* be1 = (const float*)d_in[4];
    const float* We2 = (const float*)d_in[5];  const float* be2 = (const float*)d_in[6];
    const float* We3 = (const float*)d_in[7];  const float* be3 = (const float*)d_in[8];
    const float* Wz  = (const float*)d_in[9];  const float* bz  = (const float*)d_in[10];
    const float* Wd1 = (const float*)d_in[11]; const float* bd1 = (const float*)d_in[12];
    const float* Wd2 = (const float*)d_in[13]; const float* bd2 = (const float*)d_in[14];
    const float* Wd3 = (const float*)d_in[15]; const float* bd3 = (const float*)d_in[16];
    const float* Wxb = (const float*)d_in[17]; const float* bxb = (const float*)d_in[18];
    float* out = (float*)d_out;

    const size_t M = M_PTS;
    float* ws   = (float*)d_ws;
    float* BIG  = ws;                          // M*2048 (h3, then d1, then x_bar)
    float* MID1 = BIG  + M*2048;               // M*512  (h1, then d2)
    float* MID2 = MID1 + M*512;                // M*512  (h2, then d3)
    float* Z    = MID2 + M*512;                // M*32
    float* WTb  = Z    + M*32;                 // transposed weights, 3801088 floats
    float* WTe1 = WTb;                         // 512x1024
    float* WTe2 = WTe1 + 512*1024;             // 512x512
    float* WTe3 = WTe2 + 512*512;              // 2048x512
    float* WTz  = WTe3 + 2048*512;             // 32x2048
    float* WTd1 = WTz  + 32*2048;              // 2048x32
    float* WTd2 = WTd1 + 2048*32;              // 512x2048
    float* WTd3 = WTd2 + 512*2048;             // 512x512
    float* WTxb = WTd3 + 512*512;              // 1024x512
    float* U    = WTxb + 1024*512;             // 100 (+pad)
    float* F    = U + 128;                     // 100 (+pad)
    int*   CNT  = (int*)(F + 128);             // 100 (+pad)
    double* DBL = (double*)(CNT + 128);        // 8 doubles

    zero_acc<<<1, 256, 0, stream>>>(U, CNT, DBL);

    // weight transposes (K, N) -> (N, K)
    transpose_w<<<dim3(512/32, 1024/32), 256, 0, stream>>>(We1, WTe1, 1024, 512);
    transpose_w<<<dim3(512/32,  512/32), 256, 0, stream>>>(We2, WTe2,  512, 512);
    transpose_w<<<dim3(2048/32, 512/32), 256, 0, stream>>>(We3, WTe3,  512, 2048);
    transpose_w<<<dim3(32/32, 2048/32),  256, 0, stream>>>(Wz,  WTz,  2048, 32);
    transpose_w<<<dim3(2048/32, 32/32),  256, 0, stream>>>(Wd1, WTd1,   32, 2048);
    transpose_w<<<dim3(512/32, 2048/32), 256, 0, stream>>>(Wd2, WTd2, 2048, 512);
    transpose_w<<<dim3(512/32,  512/32), 256, 0, stream>>>(Wd3, WTd3,  512, 512);
    transpose_w<<<dim3(1024/32, 512/32), 256, 0, stream>>>(Wxb, WTxb,  512, 1024);

    const int MB = M_PTS/128;  // 232
    // h1 = relu(x @ We1 + be1)
    gemm_mfma<2,2,4,4,true ><<<dim3(512/128,  MB), 256, 0, stream>>>(x,    WTe1, be1, MID1, M, 512,  1024);
    // h2 = relu(h1 @ We2 + be2)
    gemm_mfma<2,2,4,4,true ><<<dim3(512/128,  MB), 256, 0, stream>>>(MID1, WTe2, be2, MID2, M, 512,  512);
    // h3 = relu(h2 @ We3 + be3)
    gemm_mfma<2,2,4,4,true ><<<dim3(2048/128, MB), 256, 0, stream>>>(MID2, WTe3, be3, BIG,  M, 2048, 512);
    // z = h3 @ Wz + bz   (N=32 config)
    gemm_mfma<4,1,2,2,false><<<dim3(1,        MB), 256, 0, stream>>>(BIG,  WTz,  bz,  Z,    M, 32,   2048);
    // d1 = relu(z @ Wd1 + bd1)
    gemm_mfma<2,2,4,4,true ><<<dim3(2048/128, MB), 256, 0, stream>>>(Z,    WTd1, bd1, BIG,  M, 2048, 32);
    // d2 = relu(d1 @ Wd2 + bd2)
    gemm_mfma<2,2,4,4,true ><<<dim3(512/128,  MB), 256, 0, stream>>>(BIG,  WTd2, bd2, MID1, M, 512,  2048);
    // d3 = relu(d2 @ Wd3 + bd3)
    gemm_mfma<2,2,4,4,true ><<<dim3(512/128,  MB), 256, 0, stream>>>(MID1, WTd3, bd3, MID2, M, 512,  512);
    // x_bar = d3 @ Wxb + bxb
    gemm_mfma<2,2,4,4,false><<<dim3(1024/128, MB), 256, 0, stream>>>(MID2, WTxb, bxb, BIG,  M, 1024, 512);

    cluster_pass<<<M_PTS/256, 256, 0, stream>>>(Z, t1c, clu, out, U, CNT, DBL + 0);
    finalize_kernel<<<1, 256, 0, stream>>>(U, CNT, DBL, clu, F, DBL);
    kl_pass<<<M_PTS/256, 256, 0, stream>>>(Z, t1c, clu, F, DBL + 1);
    re_pass<<<1024, 256, 0, stream>>>(BIG, x, DBL + 2, (int)(M*N_IN_DIM));
    final_loss<<<1, 1, 0, stream>>>(DBL, out + M_PTS);
}

// Round 3
// 1562.804 us; speedup vs baseline: 2.4196x; 1.1087x over previous
//
#include <hip/hip_runtime.h>
#include <math.h>

#define M_PTS 29696
#define N_IN_DIM 1024
#define KCL 100
#define NZ_DIM 32

typedef _Float16 h8 __attribute__((ext_vector_type(8)));
typedef _Float16 h4 __attribute__((ext_vector_type(4)));
typedef float f4 __attribute__((ext_vector_type(4)));

// ---------------- weight transpose: W (KxN) -> WT (NxK), fp32 ----------------
__global__ __launch_bounds__(256)
void transpose_w(const float* __restrict__ W, float* __restrict__ WT, int K, int N)
{
    __shared__ float t[32][33];
    const int tid = threadIdx.x;
    const int n0 = blockIdx.x * 32, k0 = blockIdx.y * 32;
    {
        int r = tid / 8, c = (tid % 8) * 4;
        const float4 v = *(const float4*)(W + (size_t)(k0 + r) * N + n0 + c);
        t[r][c+0] = v.x; t[r][c+1] = v.y; t[r][c+2] = v.z; t[r][c+3] = v.w;
    }
    __syncthreads();
    {
        int r = tid / 8, c = (tid % 8) * 4;   // r = n idx, c = k idx
        float4 v;
        v.x = t[c+0][r]; v.y = t[c+1][r]; v.z = t[c+2][r]; v.w = t[c+3][r];
        *(float4*)(WT + (size_t)(n0 + r) * K + k0 + c) = v;
    }
}

// ---------------- MFMA GEMM: C = act(A @ WT^T + bias), f16x3 split ----------------
template<int WM, int WN, int TM, int TN, bool RELU>
__global__ __launch_bounds__(WM*WN*64)
void gemm_mfma(const float* __restrict__ A, const float* __restrict__ WT,
               const float* __restrict__ bias, float* __restrict__ C,
               int M, int N, int K)
{
    constexpr int BM = WM*TM*16;
    constexpr int BN = WN*TN*16;
    constexpr int THREADS = WM*WN*64;
    constexpr int LDK = 40;
    __shared__ __align__(16) _Float16 Ah[BM*LDK];
    __shared__ __align__(16) _Float16 Al[BM*LDK];
    __shared__ __align__(16) _Float16 Bh[BN*LDK];
    __shared__ __align__(16) _Float16 Bl[BN*LDK];

    const int tid = threadIdx.x;
    const int bm0 = blockIdx.y * BM;
    const int bn0 = blockIdx.x * BN;
    const int wave = tid >> 6, lane = tid & 63;
    const int wm = wave / WN, wn = wave % WN;
    const int lrow = lane & 15, lq = lane >> 4;

    f4 acc[TM][TN];
    #pragma unroll
    for (int i = 0; i < TM; ++i)
        #pragma unroll
        for (int j = 0; j < TN; ++j)
            acc[i][j] = (f4)0.0f;

    for (int k0 = 0; k0 < K; k0 += 32) {
        __syncthreads();
        #pragma unroll
        for (int it = 0; it < (BM*32)/(THREADS*4); ++it) {
            int idx = (tid + it*THREADS) * 4;
            int r = idx >> 5, c = idx & 31;
            const float4 v = *(const float4*)(A + (size_t)(bm0 + r)*K + k0 + c);
            float vv[4] = {v.x, v.y, v.z, v.w};
            h4 hi, lo;
            #pragma unroll
            for (int u = 0; u < 4; ++u) {
                _Float16 h = (_Float16)vv[u];
                hi[u] = h;
                lo[u] = (_Float16)(vv[u] - (float)h);
            }
            *(h4*)(&Ah[r*LDK + c]) = hi;
            *(h4*)(&Al[r*LDK + c]) = lo;
        }
        #pragma unroll
        for (int it = 0; it < (BN*32)/(THREADS*4); ++it) {
            int idx = (tid + it*THREADS) * 4;
            int r = idx >> 5, c = idx & 31;
            const float4 v = *(const float4*)(WT + (size_t)(bn0 + r)*K + k0 + c);
            float vv[4] = {v.x, v.y, v.z, v.w};
            h4 hi, lo;
            #pragma unroll
            for (int u = 0; u < 4; ++u) {
                _Float16 h = (_Float16)vv[u];
                hi[u] = h;
                lo[u] = (_Float16)(vv[u] - (float)h);
            }
            *(h4*)(&Bh[r*LDK + c]) = hi;
            *(h4*)(&Bl[r*LDK + c]) = lo;
        }
        __syncthreads();
        h8 ah[TM], al[TM], bh[TN], bl[TN];
        #pragma unroll
        for (int i = 0; i < TM; ++i) {
            int row = (wm*TM + i)*16 + lrow;
            ah[i] = *(const h8*)(&Ah[row*LDK + lq*8]);
            al[i] = *(const h8*)(&Al[row*LDK + lq*8]);
        }
        #pragma unroll
        for (int j = 0; j < TN; ++j) {
            int row = (wn*TN + j)*16 + lrow;
            bh[j] = *(const h8*)(&Bh[row*LDK + lq*8]);
            bl[j] = *(const h8*)(&Bl[row*LDK + lq*8]);
        }
        #pragma unroll
        for (int i = 0; i < TM; ++i)
            #pragma unroll
            for (int j = 0; j < TN; ++j)
                acc[i][j] = __builtin_amdgcn_mfma_f32_16x16x32_f16(ah[i], bh[j], acc[i][j], 0, 0, 0);
        #pragma unroll
        for (int i = 0; i < TM; ++i)
            #pragma unroll
            for (int j = 0; j < TN; ++j)
                acc[i][j] = __builtin_amdgcn_mfma_f32_16x16x32_f16(ah[i], bl[j], acc[i][j], 0, 0, 0);
        #pragma unroll
        for (int i = 0; i < TM; ++i)
            #pragma unroll
            for (int j = 0; j < TN; ++j)
                acc[i][j] = __builtin_amdgcn_mfma_f32_16x16x32_f16(al[i], bh[j], acc[i][j], 0, 0, 0);
    }
    #pragma unroll
    for (int j = 0; j < TN; ++j) {
        int col = bn0 + (wn*TN + j)*16 + lrow;
        float bj = bias[col];
        #pragma unroll
        for (int i = 0; i < TM; ++i) {
            int rbase = bm0 + (wm*TM + i)*16 + lq*4;
            #pragma unroll
            for (int r = 0; r < 4; ++r) {
                float v = acc[i][j][r] + bj;
                if (RELU) v = fmaxf(v, 0.0f);
                C[(size_t)(rbase + r)*N + col] = v;
            }
        }
    }
}

// ---------------- accumulator zeroing ----------------
__global__ void zero_acc(float* __restrict__ u, int* __restrict__ cnt, double* __restrict__ dbl)
{
    int t = threadIdx.x;
    if (t < KCL) { u[t] = 0.0f; cnt[t] = 0; }
    if (t < 8) dbl[t] = 0.0;
}

// ---------------- clustering pass: 4 threads per point ----------------
// thread kg=tid&3 owns k = kg + 4*j, j in [0,25). Computes dist once into regs,
// stores val-row (D) and rowsum for kl_pass, argmax via quad shuffle,
// u via cross-quad shuffle reduction (conflict-free LDS atomics from 4 lanes).
__global__ __launch_bounds__(256)
void cluster_pass(const float* __restrict__ z, const float* __restrict__ t1,
                  const float* __restrict__ clusters,
                  float* __restrict__ D, float* __restrict__ ROWSUM,
                  float* __restrict__ pred_out, float* __restrict__ u_acc,
                  int* __restrict__ cnt, double* __restrict__ S_acc)
{
    __shared__ float cl[KCL*33];       // padded stride 33: quad lanes hit distinct banks
    __shared__ float u_s[KCL];
    __shared__ float swave[4];
    const int tid = threadIdx.x;
    const int lane = tid & 63;
    for (int i = tid; i < KCL*NZ_DIM; i += 256) cl[(i >> 5)*33 + (i & 31)] = clusters[i];
    if (tid < KCL) u_s[tid] = 0.0f;
    __syncthreads();

    const int p  = (blockIdx.x*256 + tid) >> 2;
    const int kg = tid & 3;

    // standardize z (each of the 4 quad lanes redundantly; loads broadcast via L1)
    float zr[NZ_DIM];
    const float a = t1[p*3+0]*0.01f, b = t1[p*3+1]*0.01f, c = t1[p*3+2]*0.01f;
    const float cm = a*b*c*0.99f + 1.0f;
    float mean = 0.0f;
    #pragma unroll
    for (int i = 0; i < NZ_DIM; ++i) { zr[i] = z[(size_t)p*NZ_DIM+i]*cm; mean += zr[i]; }
    mean *= (1.0f/NZ_DIM);
    float var = 0.0f;
    #pragma unroll
    for (int i = 0; i < NZ_DIM; ++i) { float d = zr[i]-mean; var += d*d; }
    const float istd = 1.0f / sqrtf(var * (1.0f/(NZ_DIM-1)));
    #pragma unroll
    for (int i = 0; i < NZ_DIM; ++i) zr[i] = (zr[i]-mean)*istd;

    // distances for my 25 k's (computed once, kept in regs)
    float vals[25];
    float rowsum = 0.0f, best = -1.0f; int bk = 0;
    #pragma unroll
    for (int j = 0; j < 25; ++j) {
        const int k = kg + 4*j;
        float d = 0.0f;
        #pragma unroll
        for (int i = 0; i < NZ_DIM; ++i) { float t = zr[i]-cl[k*33+i]; d = fmaf(t,t,d); }
        float val = 1e-5f + d;
        vals[j] = val;
        rowsum += val;
        if (val > best) { best = val; bk = k; }
        D[(size_t)p*KCL + k] = val;
    }
    // quad reductions (lanes kg=0..3 of each point)
    rowsum += __shfl_xor(rowsum, 1);
    rowsum += __shfl_xor(rowsum, 2);
    #pragma unroll
    for (int m = 1; m <= 2; m <<= 1) {
        float ov = __shfl_xor(best, m);
        int   ok = __shfl_xor(bk, m);
        if (ov > best || (ov == best && ok < bk)) { best = ov; bk = ok; }
    }
    if (kg == 0) {
        pred_out[p] = (float)bk;
        atomicAdd(&cnt[bk], 1);
        ROWSUM[p] = rowsum;
    }

    // u and S
    const float inv_rs = 1.0f/rowsum;
    float Sp = 0.0f;
    #pragma unroll
    for (int j = 0; j < 25; ++j) {
        float qv = vals[j]*inv_rs;
        float lq = logf(qv);
        float om = 1.0f - qv;
        Sp += sqrtf(-1.0f/(om*om*lq*(float)M_PTS));
        // sum qv across the 16 quads of this wave -> lanes 0..3 hold per-k totals
        float qs = qv;
        qs += __shfl_xor(qs, 4);
        qs += __shfl_xor(qs, 8);
        qs += __shfl_xor(qs, 16);
        qs += __shfl_xor(qs, 32);
        if (lane < 4) atomicAdd(&u_s[lane + 4*j], qs);
    }
    for (int off = 32; off > 0; off >>= 1) Sp += __shfl_down(Sp, off, 64);
    if (lane == 0) swave[tid >> 6] = Sp;
    __syncthreads();
    if (tid < KCL) atomicAdd(&u_acc[tid], u_s[tid]);
    if (tid == 0) atomicAdd(S_acc, (double)(swave[0]+swave[1]+swave[2]+swave[3]));
}

// ---------------- block reduction helpers (256 threads) ----------------
__device__ __forceinline__ float blk_sum(float v, float* sh) {
    int tid = threadIdx.x;
    sh[tid] = v; __syncthreads();
    for (int s = 128; s > 0; s >>= 1) { if (tid < s) sh[tid] += sh[tid+s]; __syncthreads(); }
    float r = sh[0]; __syncthreads();
    return r;
}
__device__ __forceinline__ float blk_min(float v, float* sh) {
    int tid = threadIdx.x;
    sh[tid] = v; __syncthreads();
    for (int s = 128; s > 0; s >>= 1) { if (tid < s) sh[tid] = fminf(sh[tid], sh[tid+s]); __syncthreads(); }
    float r = sh[0]; __syncthreads();
    return r;
}

// ---------------- finalize u, v, f and u_loss ----------------
__global__ __launch_bounds__(256)
void finalize_kernel(const float* __restrict__ u_in, const int* __restrict__ cnt,
                     const double* __restrict__ dbl, const float* __restrict__ clusters,
                     float* __restrict__ f_out, double* __restrict__ dbl_out)
{
    __shared__ float sh[256];
    __shared__ double shd[256];
    const int tid = threadIdx.x;
    const bool act = (tid < KCL);
    const float S = (float)dbl[0];

    float uv = act ? u_in[tid] : 0.0f;
    float um = blk_sum(uv, sh) * (1.0f/KCL);
    float ud = act ? (uv - um) : 0.0f;
    float uvar = blk_sum(ud*ud, sh) * (1.0f/(KCL-1));
    float un = ud / sqrtf(uvar);
    float umin = blk_min(act ? un : 3.0e38f, sh);
    float ufin = un - umin + 0.001f;

    float vv = 0.0f;
    if (act) { int cc = cnt[tid]; if (cc < 1) cc = 1; vv = sqrtf((float)cc) * S; }
    float vm = blk_sum(vv, sh) * (1.0f/KCL);
    float vd = act ? (vv - vm) : 0.0f;
    float vvar = blk_sum(vd*vd, sh) * (1.0f/(KCL-1));
    float vn = vd / sqrtf(vvar);
    float vmin = blk_min(act ? vn : 3.0e38f, sh);
    float vfin = vn - vmin + 0.001f;

    if (act) f_out[tid] = ufin + vfin + 1.0f;

    double dp = 0.0;
    for (int pair = tid; pair < KCL*KCL; pair += 256) {
        int i = pair / KCL, j = pair % KCL;
        float d = 0.0f;
        #pragma unroll
        for (int t2 = 0; t2 < NZ_DIM; ++t2) {
            float x = clusters[i*NZ_DIM+t2] - clusters[j*NZ_DIM+t2];
            d = fmaf(x, x, d);
        }
        dp += (double)d;
    }
    shd[tid] = dp; __syncthreads();
    for (int s = 128; s > 0; s >>= 1) { if (tid < s) shd[tid] += shd[tid+s]; __syncthreads(); }
    if (tid == 0) {
        dbl_out[3] = 0.01 * (double)(KCL*KCL - KCL) / shd[0];
    }
}

// ---------------- KL pass: 4 threads per point, reads stored D/ROWSUM ----------------
__global__ __launch_bounds__(256)
void kl_pass(const float* __restrict__ D, const float* __restrict__ ROWSUM,
             const float* __restrict__ f, double* __restrict__ kl_acc)
{
    __shared__ float fs[KCL], lfs[KCL];
    __shared__ float swave[4];
    const int tid = threadIdx.x;
    const int lane = tid & 63;
    if (tid < KCL) { float fv = f[tid]; fs[tid] = fv; lfs[tid] = logf(fv); }
    __syncthreads();

    const int p  = (blockIdx.x*256 + tid) >> 2;
    const int kg = tid & 3;

    float vals[25];
    #pragma unroll
    for (int j = 0; j < 25; ++j) vals[j] = D[(size_t)p*KCL + kg + 4*j];

    float sv = 0.0f;
    #pragma unroll
    for (int j = 0; j < 25; ++j) { float v = vals[j]; sv += v*v/fs[kg + 4*j]; }
    sv += __shfl_xor(sv, 1);
    sv += __shfl_xor(sv, 2);

    const float rowsum = ROWSUM[p];
    const float lrs = logf(rowsum), lsv = logf(sv);
    const float inv_sv = 1.0f/sv;
    float klp = 0.0f;
    #pragma unroll
    for (int j = 0; j < 25; ++j) {
        const int k = kg + 4*j;
        float v = vals[j];
        float pv = v*v/fs[k]*inv_sv;
        klp += pv*(logf(v) - lfs[k] - lsv + lrs);
    }
    for (int off = 32; off > 0; off >>= 1) klp += __shfl_down(klp, off, 64);
    if (lane == 0) swave[tid >> 6] = klp;
    __syncthreads();
    if (tid == 0) atomicAdd(kl_acc, (double)(swave[0]+swave[1]+swave[2]+swave[3]));
}

// ---------------- reconstruction loss pass ----------------
__global__ __launch_bounds__(256)
void re_pass(const float* __restrict__ xb, const float* __restrict__ x,
             double* __restrict__ acc, int n)
{
    __shared__ float swave[4];
    float part = 0.0f;
    for (size_t i = (size_t)blockIdx.x*blockDim.x + threadIdx.x; i < (size_t)n;
         i += (size_t)gridDim.x*blockDim.x) {
        float d = xb[i] - x[i];
        part = fmaf(d, d, part);
    }
    for (int off = 32; off > 0; off >>= 1) part += __shfl_down(part, off, 64);
    const int tid = threadIdx.x;
    if ((tid & 63) == 0) swave[tid >> 6] = part;
    __syncthreads();
    if (tid == 0) atomicAdd(acc, (double)(swave[0]+swave[1]+swave[2]+swave[3]));
}

// ---------------- final loss ----------------
__global__ void final_loss(const double* __restrict__ dbl, float* __restrict__ out)
{
    double kl = dbl[1] / (double)((size_t)M_PTS*KCL) * 0.01;
    double re = dbl[2] / (double)((size_t)M_PTS*N_IN_DIM);
    out[0] = (float)(kl + re + dbl[3]);
}

extern "C" void kernel_launch(void* const* d_in, const int* in_sizes, int n_in,
                              void* d_out, int out_size, void* d_ws, size_t ws_size,
                              hipStream_t stream)
{
    const float* x   = (const float*)d_in[0];
    const float* t1c = (const float*)d_in[1];
    const float* clu = (const float*)d_in[2];
    const float* We1 = (const float*)d_in[3];  const float* be1 = (const float*)d_in[4];
    const float* We2 = (const float*)d_in[5];  const float* be2 = (const float*)d_in[6];
    const float* We3 = (const float*)d_in[7];  const float* be3 = (const float*)d_in[8];
    const float* Wz  = (const float*)d_in[9];  const float* bz  = (const float*)d_in[10];
    const float* Wd1 = (const float*)d_in[11]; const float* bd1 = (const float*)d_in[12];
    const float* Wd2 = (const float*)d_in[13]; const float* bd2 = (const float*)d_in[14];
    const float* Wd3 = (const float*)d_in[15]; const float* bd3 = (const float*)d_in[16];
    const float* Wxb = (const float*)d_in[17]; const float* bxb = (const float*)d_in[18];
    float* out = (float*)d_out;

    const size_t M = M_PTS;
    float* ws   = (float*)d_ws;
    float* BIG  = ws;                          // M*2048 (h3, then d1, then x_bar)
    float* MID1 = BIG  + M*2048;               // M*512  (h1, then d2; then D+ROWSUM)
    float* MID2 = MID1 + M*512;                // M*512  (h2, then d3)
    float* Z    = MID2 + M*512;                // M*32
    float* WTb  = Z    + M*32;
    float* WTe1 = WTb;                         // 512x1024
    float* WTe2 = WTe1 + 512*1024;             // 512x512
    float* WTe3 = WTe2 + 512*512;              // 2048x512
    float* WTz  = WTe3 + 2048*512;             // 32x2048
    float* WTd1 = WTz  + 32*2048;              // 2048x32
    float* WTd2 = WTd1 + 2048*32;              // 512x2048
    float* WTd3 = WTd2 + 512*2048;             // 512x512
    float* WTxb = WTd3 + 512*512;              // 1024x512
    float* U    = WTxb + 1024*512;             // 100 (+pad)
    float* F    = U + 128;                     // 100 (+pad)
    int*   CNT  = (int*)(F + 128);             // 100 (+pad)
    double* DBL = (double*)(CNT + 128);        // 8 doubles

    // D (M*100) and ROWSUM (M) reuse MID1 — d2 is dead once d3 exists.
    float* Dm  = MID1;
    float* RSm = MID1 + M*KCL;

    zero_acc<<<1, 256, 0, stream>>>(U, CNT, DBL);

    transpose_w<<<dim3(512/32, 1024/32), 256, 0, stream>>>(We1, WTe1, 1024, 512);
    transpose_w<<<dim3(512/32,  512/32), 256, 0, stream>>>(We2, WTe2,  512, 512);
    transpose_w<<<dim3(2048/32, 512/32), 256, 0, stream>>>(We3, WTe3,  512, 2048);
    transpose_w<<<dim3(32/32, 2048/32),  256, 0, stream>>>(Wz,  WTz,  2048, 32);
    transpose_w<<<dim3(2048/32, 32/32),  256, 0, stream>>>(Wd1, WTd1,   32, 2048);
    transpose_w<<<dim3(512/32, 2048/32), 256, 0, stream>>>(Wd2, WTd2, 2048, 512);
    transpose_w<<<dim3(512/32,  512/32), 256, 0, stream>>>(Wd3, WTd3,  512, 512);
    transpose_w<<<dim3(1024/32, 512/32), 256, 0, stream>>>(Wxb, WTxb,  512, 1024);

    const int MB = M_PTS/128;  // 232
    gemm_mfma<2,2,4,4,true ><<<dim3(512/128,  MB), 256, 0, stream>>>(x,    WTe1, be1, MID1, M, 512,  1024);
    gemm_mfma<2,2,4,4,true ><<<dim3(512/128,  MB), 256, 0, stream>>>(MID1, WTe2, be2, MID2, M, 512,  512);
    gemm_mfma<2,2,4,4,true ><<<dim3(2048/128, MB), 256, 0, stream>>>(MID2, WTe3, be3, BIG,  M, 2048, 512);
    gemm_mfma<4,1,2,2,false><<<dim3(1,        MB), 256, 0, stream>>>(BIG,  WTz,  bz,  Z,    M, 32,   2048);
    gemm_mfma<2,2,4,4,true ><<<dim3(2048/128, MB), 256, 0, stream>>>(Z,    WTd1, bd1, BIG,  M, 2048, 32);
    gemm_mfma<2,2,4,4,true ><<<dim3(512/128,  MB), 256, 0, stream>>>(BIG,  WTd2, bd2, MID1, M, 512,  2048);
    gemm_mfma<2,2,4,4,true ><<<dim3(512/128,  MB), 256, 0, stream>>>(MID1, WTd3, bd3, MID2, M, 512,  512);
    gemm_mfma<2,2,4,4,false><<<dim3(1024/128, MB), 256, 0, stream>>>(MID2, WTxb, bxb, BIG,  M, 1024, 512);

    const int PB = (M_PTS*4)/256;   // 464 blocks, 4 threads per point
    cluster_pass<<<PB, 256, 0, stream>>>(Z, t1c, clu, Dm, RSm, out, U, CNT, DBL + 0);
    finalize_kernel<<<1, 256, 0, stream>>>(U, CNT, DBL, clu, F, DBL);
    kl_pass<<<PB, 256, 0, stream>>>(Dm, RSm, F, DBL + 1);
    re_pass<<<1024, 256, 0, stream>>>(BIG, x, DBL + 2, (int)(M*N_IN_DIM));
    final_loss<<<1, 1, 0, stream>>>(DBL, out + M_PTS);
}